// Round 4
// baseline (1751.498 us; speedup 1.0000x reference)
//
#include <hip/hip_runtime.h>
#include <hip/hip_bf16.h>
#include <stdint.h>

#define NUM_B   16384
#define FIELDS  23
#define EMBD    128
#define FEATD   2944   // 23*128
#define NEXP    8
#define ESIZE   1024
#define TSIZE   512
#define NGATE   3

using short8 = __attribute__((ext_vector_type(8))) short;
using f32x4  = __attribute__((ext_vector_type(4))) float;

__device__ __forceinline__ unsigned short f2bf(float x) {
  union { float f; unsigned u; } c; c.f = x;
  unsigned r = (c.u + 0x7fffu + ((c.u >> 16) & 1u)) >> 16;
  return (unsigned short)r;
}
__device__ __forceinline__ float bf2f(unsigned short x) {
  union { unsigned u; float f; } c; c.u = ((unsigned)x) << 16;
  return c.f;
}

__device__ __forceinline__ void g2l16(const void* g, void* l) {
  __builtin_amdgcn_global_load_lds(
      (const __attribute__((address_space(1))) void*)g,
      (__attribute__((address_space(3))) void*)l,
      16, 0, 0);
}

// ---------------------------------------------------------------------------
// W: transpose f32 [z][R][C] -> bf16 [z][C][R]
// ---------------------------------------------------------------------------
__global__ __launch_bounds__(256) void k_transpose(const float* __restrict__ src,
                                                   unsigned short* __restrict__ dst,
                                                   int R, int C) {
  long zoff = (long)blockIdx.z * R * C;
  src += zoff; dst += zoff;
  __shared__ float t[32][33];
  int tx = threadIdx.x, ty = threadIdx.y;
  int r0 = blockIdx.y * 32, c0 = blockIdx.x * 32;
#pragma unroll
  for (int i = 0; i < 4; ++i) {
    int r = r0 + ty + i * 8;
    t[ty + i * 8][tx] = src[(long)r * C + c0 + tx];
  }
  __syncthreads();
#pragma unroll
  for (int i = 0; i < 4; ++i) {
    int c = c0 + ty + i * 8;
    dst[(long)c * R + r0 + tx] = f2bf(t[tx][ty + i * 8]);
  }
}

// ---------------------------------------------------------------------------
// K1: embedding gather + seq-pool -> concat bf16 [Bc][2944] (local rows)
//     grid (Bc/8, FIELDS); 8 b's per block, 32 lanes x float4 each
// ---------------------------------------------------------------------------
__global__ __launch_bounds__(256) void k1_pool(const int* __restrict__ idx,
                                               const float* __restrict__ emb,
                                               unsigned short* __restrict__ concat,
                                               int b0) {
  int tid = threadIdx.x;
  int p = tid >> 5, l = tid & 31;
  int f = blockIdx.y;
  int bl = blockIdx.x * 8 + p;                // local row
  int b = b0 + bl;                            // global batch index
  const int* ip = idx + ((long)f * NUM_B + b) * 3;
  long i0 = ip[0], i1 = ip[1], i2 = ip[2];
  float4 a = *((const float4*)(emb + i0 * EMBD) + l);
  float4 c = *((const float4*)(emb + i1 * EMBD) + l);
  float4 d = *((const float4*)(emb + i2 * EMBD) + l);
  float sx = a.x + c.x + d.x, sy = a.y + c.y + d.y;
  float sz = a.z + c.z + d.z, sw = a.w + c.w + d.w;
  ushort4 o;
  o.x = f2bf(sx); o.y = f2bf(sy); o.z = f2bf(sz); o.w = f2bf(sw);
  *(ushort4*)(concat + (long)bl * FEATD + f * EMBD + l * 4) = o;
}

// ---------------------------------------------------------------------------
// K2: gates = softmax(concat @ gate_w + gate_b) -> [Bc][24] f32 (local rows)
// ---------------------------------------------------------------------------
__global__ __launch_bounds__(256) void k2_gates(const unsigned short* __restrict__ concat,
                                                const float* __restrict__ gw,
                                                const float* __restrict__ gb,
                                                float* __restrict__ gates) {
  __shared__ float part[4][64][24];
  int tid = threadIdx.x;
  int r = tid & 63;
  int q = __builtin_amdgcn_readfirstlane(tid >> 6);
  int bl = blockIdx.x * 64 + r;
  float acc[24];
#pragma unroll
  for (int i = 0; i < 24; ++i) acc[i] = 0.f;
  const int kpt = FEATD / 4;          // 736
  int k0 = q * kpt;
  const unsigned short* arow = concat + (long)bl * FEATD;
  for (int kk = k0; kk < k0 + kpt; kk += 8) {
    short8 a8 = *(const short8*)(arow + kk);
    const float* w0 = gw + (long)kk * 8;
#pragma unroll
    for (int jj = 0; jj < 8; ++jj) {
      float av = bf2f((unsigned short)a8[jj]);
      const float* wp = w0 + jj * 8;
#pragma unroll
      for (int e = 0; e < 8; ++e) {
        acc[e]      += av * wp[e];
        acc[8 + e]  += av * wp[FEATD * 8 + e];
        acc[16 + e] += av * wp[2 * FEATD * 8 + e];
      }
    }
  }
#pragma unroll
  for (int i = 0; i < 24; ++i) part[q][r][i] = acc[i];
  __syncthreads();
  if (tid < 64) {
    float tot[24];
#pragma unroll
    for (int i = 0; i < 24; ++i)
      tot[i] = part[0][tid][i] + part[1][tid][i] + part[2][tid][i] + part[3][tid][i] + gb[i];
    float* gout = gates + (long)(blockIdx.x * 64 + tid) * 24;
#pragma unroll
    for (int g = 0; g < 3; ++g) {
      float m = tot[g * 8];
#pragma unroll
      for (int e = 1; e < 8; ++e) m = fmaxf(m, tot[g * 8 + e]);
      float ex[8]; float s = 0.f;
#pragma unroll
      for (int e = 0; e < 8; ++e) { ex[e] = expf(tot[g * 8 + e] - m); s += ex[e]; }
      float inv = 1.f / s;
#pragma unroll
      for (int e = 0; e < 8; ++e) gout[g * 8 + e] = ex[e] * inv;
    }
  }
}

// ---------------------------------------------------------------------------
// GEMM (m97 structure): C = relu(A @ Bt^T + bias), bf16 in/out, f32 acc
//   A  [M][K] bf16 row-major; Bt [N][K] bf16 row-major (B transposed)
//   128x128 tile, BK=32, 4 waves, 16x16x32 MFMA, global_load_lds w=16
// ---------------------------------------------------------------------------
__global__ __launch_bounds__(256) void gemm_bt(
    const unsigned short* __restrict__ A, long sA,
    const unsigned short* __restrict__ Bt, long sB,
    const float* __restrict__ bias, long sBias,
    unsigned short* __restrict__ C, long sC,
    int K, int ldc) {
  const int z = blockIdx.z;
  A += (long)z * sA; Bt += (long)z * sB; bias += (long)z * sBias; C += (long)z * sC;
  const int tid = threadIdx.x;
  const int wid = tid >> 6, lane = tid & 63;
  const int wm = wid >> 1, wn = wid & 1;
  const long bm = (long)blockIdx.x * 128, bn = (long)blockIdx.y * 128;

  __shared__ unsigned short lA[128 * 32];
  __shared__ unsigned short lB[128 * 32];

  f32x4 acc[4][4];
#pragma unroll
  for (int i = 0; i < 4; ++i)
#pragma unroll
    for (int j = 0; j < 4; ++j) acc[i][j] = (f32x4){0.f, 0.f, 0.f, 0.f};

  const int rowS = wid * 32 + (lane >> 2);
  const int kinS = (lane & 3) * 8;
  const unsigned short* gA = A + (bm + rowS) * K + kinS;
  const unsigned short* gB = Bt + (bn + rowS) * K + kinS;
  unsigned short* dA = lA + wid * 1024;   // wave-uniform LDS base
  unsigned short* dB = lB + wid * 1024;

  const int a_read = (wm * 64 + (lane & 15)) * 32 + (lane >> 4) * 8;
  const int b_read = (wn * 64 + (lane & 15)) * 32 + (lane >> 4) * 8;

  for (int kt = 0; kt < K; kt += 32) {
    g2l16(gA, dA);
    g2l16(gA + (long)16 * K, dA + 512);
    g2l16(gB, dB);
    g2l16(gB + (long)16 * K, dB + 512);
    gA += 32; gB += 32;
    __syncthreads();
    short8 aF[4], bF[4];
#pragma unroll
    for (int i = 0; i < 4; ++i) aF[i] = *(const short8*)(lA + a_read + i * 512);
#pragma unroll
    for (int j = 0; j < 4; ++j) bF[j] = *(const short8*)(lB + b_read + j * 512);
#pragma unroll
    for (int i = 0; i < 4; ++i)
#pragma unroll
      for (int j = 0; j < 4; ++j)
        acc[i][j] = __builtin_amdgcn_mfma_f32_16x16x32_bf16(aF[i], bF[j], acc[i][j], 0, 0, 0);
    __syncthreads();
  }

#pragma unroll
  for (int i = 0; i < 4; ++i) {
    long row0 = bm + wm * 64 + i * 16 + (lane >> 4) * 4;
#pragma unroll
    for (int j = 0; j < 4; ++j) {
      long col = bn + wn * 64 + j * 16 + (lane & 15);
      float bv = bias[col];
#pragma unroll
      for (int r = 0; r < 4; ++r) {
        float v = acc[i][j][r] + bv;
        v = fmaxf(v, 0.f);
        C[(row0 + r) * ldc + col] = f2bf(v);
      }
    }
  }
}

// ---------------------------------------------------------------------------
// K4: mixed[g][bl][h] = sum_e gates[bl][g][e] * eo[bl][e][h]   (bf16 out)
// ---------------------------------------------------------------------------
__global__ __launch_bounds__(256) void k4_mix(const unsigned short* __restrict__ eo,
                                              const float* __restrict__ gates,
                                              unsigned short* __restrict__ mixed,
                                              int Bc) {
  int tid = threadIdx.x;
  int bl = blockIdx.x * 2 + (tid >> 7);
  int h8 = (tid & 127) * 8;
  const float* gp = gates + (long)bl * 24;
  float o0[8], o1[8], o2[8];
#pragma unroll
  for (int x = 0; x < 8; ++x) { o0[x] = 0.f; o1[x] = 0.f; o2[x] = 0.f; }
  const unsigned short* ep = eo + (long)bl * (NEXP * ESIZE) + h8;
#pragma unroll
  for (int e = 0; e < 8; ++e) {
    short8 v = *(const short8*)(ep + e * ESIZE);
    float g0 = gp[e], g1 = gp[8 + e], g2 = gp[16 + e];
#pragma unroll
    for (int x = 0; x < 8; ++x) {
      float fv = bf2f((unsigned short)v[x]);
      o0[x] += g0 * fv; o1[x] += g1 * fv; o2[x] += g2 * fv;
    }
  }
  long base = (long)bl * ESIZE + h8;
  short8 w0, w1, w2;
#pragma unroll
  for (int x = 0; x < 8; ++x) {
    w0[x] = (short)f2bf(o0[x]); w1[x] = (short)f2bf(o1[x]); w2[x] = (short)f2bf(o2[x]);
  }
  *(short8*)(mixed + base) = w0;
  *(short8*)(mixed + (long)Bc * ESIZE + base) = w1;
  *(short8*)(mixed + 2L * Bc * ESIZE + base) = w2;
}

// ---------------------------------------------------------------------------
// K6: out head: logits = tower[g][bl] @ out_w[g] + out_b[g]; softmax2; clip;
//     assemble the 7 outputs (global offsets). One wave per b.
// ---------------------------------------------------------------------------
__global__ __launch_bounds__(256) void k6_out(const unsigned short* __restrict__ tower,
                                              const float* __restrict__ ow,
                                              const float* __restrict__ ob,
                                              float* __restrict__ out,
                                              int b0, int Bc) {
  int tid = threadIdx.x;
  int wid = tid >> 6, lane = tid & 63;
  int bl = blockIdx.x * 4 + wid;
  long b = (long)b0 + bl;
  float l0[3], l1[3];
#pragma unroll
  for (int g = 0; g < 3; ++g) {
    short8 t8 = *(const short8*)(tower + ((long)g * Bc + bl) * TSIZE + lane * 8);
    const float2* wp = (const float2*)(ow + g * (TSIZE * 2)) + lane * 8;
    float s0 = 0.f, s1 = 0.f;
#pragma unroll
    for (int x = 0; x < 8; ++x) {
      float a = bf2f((unsigned short)t8[x]);
      float2 w = wp[x];
      s0 += a * w.x; s1 += a * w.y;
    }
#pragma unroll
    for (int off = 32; off > 0; off >>= 1) {
      s0 += __shfl_xor(s0, off);
      s1 += __shfl_xor(s1, off);
    }
    l0[g] = s0 + ob[g * 2];
    l1[g] = s1 + ob[g * 2 + 1];
  }
  if (lane == 0) {
    float p0[3], p1[3];
#pragma unroll
    for (int g = 0; g < 3; ++g) {
      float d = l1[g] - l0[g];
      float e1 = 1.f / (1.f + expf(-d));
      float e0 = 1.f / (1.f + expf(d));
      p0[g] = fminf(fmaxf(e0, 1e-15f), 1.f - 1e-15f);
      p1[g] = fminf(fmaxf(e1, 1e-15f), 1.f - 1e-15f);
    }
    float ct = p1[0] * p1[1];
    out[b * 2]              = p0[0];
    out[b * 2 + 1]          = p1[0];
    out[32768 + b]          = p1[0];
    out[49152 + b * 2]      = p0[1];
    out[49152 + b * 2 + 1]  = p1[1];
    out[81920 + b]          = p1[1];
    out[98304 + b * 2]      = 1.f - ct;
    out[98304 + b * 2 + 1]  = ct;
    out[131072 + b]         = ct;
    out[147456 + b]         = p1[2];
  }
}

// ---------------------------------------------------------------------------
extern "C" void kernel_launch(void* const* d_in, const int* in_sizes, int n_in,
                              void* d_out, int out_size, void* d_ws, size_t ws_size,
                              hipStream_t stream) {
  (void)in_sizes; (void)n_in; (void)out_size;
  const int*   idx      = (const int*)d_in[0];
  const float* emb      = (const float*)d_in[1];
  const float* expert_w = (const float*)d_in[2];
  const float* expert_b = (const float*)d_in[3];
  const float* gate_w   = (const float*)d_in[4];
  const float* gate_b   = (const float*)d_in[5];
  const float* tower_w  = (const float*)d_in[6];
  const float* tower_b  = (const float*)d_in[7];
  const float* out_w    = (const float*)d_in[8];
  const float* out_b    = (const float*)d_in[9];
  float* out = (float*)d_out;

  // ---- workspace sizing: persistent weights + per-chunk regions (no overlays)
  const size_t P_EOW  = (size_t)NEXP * ESIZE * FEATD * 2;    // 48,234,496
  const size_t P_TWT  = (size_t)NGATE * TSIZE * ESIZE * 2;   //  3,145,728
  const size_t P      = P_EOW + P_TWT;                       // 51,380,224
  // per-batch-row bytes: concat 5888 + gates 96 + eo 16384 + mixed 6144 + tower 3072
  const size_t PER_B  = 31584;
  int NC = 1;
  while (NC < 64 && P + (size_t)(NUM_B / NC) * PER_B > ws_size) NC <<= 1;
  if (P + (size_t)(NUM_B / NC) * PER_B > ws_size) return;    // can't fit: clean numeric fail, no OOB
  const int Bc = NUM_B / NC;

  char* ws = (char*)d_ws;
  unsigned short* eoW     = (unsigned short*)(ws);
  unsigned short* towerWt = (unsigned short*)(ws + P_EOW);
  size_t off = P;
  unsigned short* concat  = (unsigned short*)(ws + off); off += (size_t)Bc * 5888;
  float*          gates   = (float*)(ws + off);          off += (size_t)Bc * 96;
  unsigned short* eo      = (unsigned short*)(ws + off); off += (size_t)Bc * 16384;
  unsigned short* mixed   = (unsigned short*)(ws + off); off += (size_t)Bc * 6144;
  unsigned short* tower   = (unsigned short*)(ws + off);

  // W1: expert_w [8][2944][1024] f32 -> eoW [8][1024][2944] bf16
  k_transpose<<<dim3(ESIZE / 32, FEATD / 32, NEXP), dim3(32, 8), 0, stream>>>(
      expert_w, eoW, FEATD, ESIZE);
  // W2: tower_w [3][1024][512] f32 -> towerWt [3][512][1024] bf16
  k_transpose<<<dim3(TSIZE / 32, ESIZE / 32, NGATE), dim3(32, 8), 0, stream>>>(
      tower_w, towerWt, ESIZE, TSIZE);

  for (int c = 0; c < NC; ++c) {
    const int b0 = c * Bc;
    // K1: pooled embeddings -> concat (local rows)
    k1_pool<<<dim3(Bc / 8, FIELDS), 256, 0, stream>>>(idx, emb, concat, b0);
    // K2: gates
    k2_gates<<<dim3(Bc / 64), 256, 0, stream>>>(concat, gate_w, gate_b, gates);
    // K3: expert GEMM (z = expert), relu+bias, eo[bl][e][h]
    gemm_bt<<<dim3(Bc / 128, ESIZE / 128, NEXP), 256, 0, stream>>>(
        concat, 0L, eoW, (long)ESIZE * FEATD, expert_b, (long)ESIZE,
        eo, (long)ESIZE, FEATD, NEXP * ESIZE);
    // K4: gate mixing -> mixed[g][bl][h]
    k4_mix<<<dim3(Bc / 2), 256, 0, stream>>>(eo, gates, mixed, Bc);
    // K5: tower GEMM (z = gate), relu+bias, tower[g][bl][t]
    gemm_bt<<<dim3(Bc / 128, TSIZE / 128, NGATE), 256, 0, stream>>>(
        mixed, (long)Bc * ESIZE, towerWt, (long)TSIZE * ESIZE, tower_b, (long)TSIZE,
        tower, (long)Bc * TSIZE, ESIZE, TSIZE);
    // K6: output head + assembly (global b offsets)
    k6_out<<<dim3(Bc / 4), 256, 0, stream>>>(tower, out_w, out_b, out, b0, Bc);
  }
}

// Round 6
// 1312.393 us; speedup vs baseline: 1.3346x; 1.3346x over previous
//
#include <hip/hip_runtime.h>
#include <hip/hip_bf16.h>
#include <stdint.h>

#define NUM_B   16384
#define FIELDS  23
#define EMBD    128
#define FEATD   2944   // 23*128
#define NEXP    8
#define ESIZE   1024
#define TSIZE   512
#define NGATE   3

using short8 = __attribute__((ext_vector_type(8))) short;
using f32x4  = __attribute__((ext_vector_type(4))) float;

__device__ __forceinline__ unsigned short f2bf(float x) {
  union { float f; unsigned u; } c; c.f = x;
  unsigned r = (c.u + 0x7fffu + ((c.u >> 16) & 1u)) >> 16;
  return (unsigned short)r;
}
__device__ __forceinline__ float bf2f(unsigned short x) {
  union { unsigned u; float f; } c; c.u = ((unsigned)x) << 16;
  return c.f;
}

__device__ __forceinline__ void g2l16(const void* g, void* l) {
  __builtin_amdgcn_global_load_lds(
      (const __attribute__((address_space(1))) void*)g,
      (__attribute__((address_space(3))) void*)l,
      16, 0, 0);
}

#define BAR()   __builtin_amdgcn_s_barrier()
#define LGKM0() asm volatile("s_waitcnt lgkmcnt(0)" ::: "memory")

// ---------------------------------------------------------------------------
// W: transpose f32 [z][R][C] -> bf16 [z][C][R]
// ---------------------------------------------------------------------------
__global__ __launch_bounds__(256) void k_transpose(const float* __restrict__ src,
                                                   unsigned short* __restrict__ dst,
                                                   int R, int C) {
  long zoff = (long)blockIdx.z * R * C;
  src += zoff; dst += zoff;
  __shared__ float t[32][33];
  int tx = threadIdx.x, ty = threadIdx.y;
  int r0 = blockIdx.y * 32, c0 = blockIdx.x * 32;
#pragma unroll
  for (int i = 0; i < 4; ++i) {
    int r = r0 + ty + i * 8;
    t[ty + i * 8][tx] = src[(long)r * C + c0 + tx];
  }
  __syncthreads();
#pragma unroll
  for (int i = 0; i < 4; ++i) {
    int c = c0 + ty + i * 8;
    dst[(long)c * R + r0 + tx] = f2bf(t[tx][ty + i * 8]);
  }
}

// ---------------------------------------------------------------------------
// K1: embedding gather + seq-pool -> concat bf16 [Bc][2944] (local rows)
// ---------------------------------------------------------------------------
__global__ __launch_bounds__(256) void k1_pool(const int* __restrict__ idx,
                                               const float* __restrict__ emb,
                                               unsigned short* __restrict__ concat,
                                               int b0) {
  int tid = threadIdx.x;
  int p = tid >> 5, l = tid & 31;
  int f = blockIdx.y;
  int bl = blockIdx.x * 8 + p;
  int b = b0 + bl;
  const int* ip = idx + ((long)f * NUM_B + b) * 3;
  long i0 = ip[0], i1 = ip[1], i2 = ip[2];
  float4 a = *((const float4*)(emb + i0 * EMBD) + l);
  float4 c = *((const float4*)(emb + i1 * EMBD) + l);
  float4 d = *((const float4*)(emb + i2 * EMBD) + l);
  float sx = a.x + c.x + d.x, sy = a.y + c.y + d.y;
  float sz = a.z + c.z + d.z, sw = a.w + c.w + d.w;
  ushort4 o;
  o.x = f2bf(sx); o.y = f2bf(sy); o.z = f2bf(sz); o.w = f2bf(sw);
  *(ushort4*)(concat + (long)bl * FEATD + f * EMBD + l * 4) = o;
}

// ---------------------------------------------------------------------------
// K2: gates = softmax(concat @ gate_w + gate_b) -> [Bc][24] f32
// ---------------------------------------------------------------------------
__global__ __launch_bounds__(256) void k2_gates(const unsigned short* __restrict__ concat,
                                                const float* __restrict__ gw,
                                                const float* __restrict__ gb,
                                                float* __restrict__ gates) {
  __shared__ float part[4][64][24];
  int tid = threadIdx.x;
  int r = tid & 63;
  int q = __builtin_amdgcn_readfirstlane(tid >> 6);
  int bl = blockIdx.x * 64 + r;
  float acc[24];
#pragma unroll
  for (int i = 0; i < 24; ++i) acc[i] = 0.f;
  const int kpt = FEATD / 4;          // 736
  int k0 = q * kpt;
  const unsigned short* arow = concat + (long)bl * FEATD;
  for (int kk = k0; kk < k0 + kpt; kk += 8) {
    short8 a8 = *(const short8*)(arow + kk);
    const float* w0 = gw + (long)kk * 8;
#pragma unroll
    for (int jj = 0; jj < 8; ++jj) {
      float av = bf2f((unsigned short)a8[jj]);
      const float* wp = w0 + jj * 8;
#pragma unroll
      for (int e = 0; e < 8; ++e) {
        acc[e]      += av * wp[e];
        acc[8 + e]  += av * wp[FEATD * 8 + e];
        acc[16 + e] += av * wp[2 * FEATD * 8 + e];
      }
    }
  }
#pragma unroll
  for (int i = 0; i < 24; ++i) part[q][r][i] = acc[i];
  __syncthreads();
  if (tid < 64) {
    float tot[24];
#pragma unroll
    for (int i = 0; i < 24; ++i)
      tot[i] = part[0][tid][i] + part[1][tid][i] + part[2][tid][i] + part[3][tid][i] + gb[i];
    float* gout = gates + (long)(blockIdx.x * 64 + tid) * 24;
#pragma unroll
    for (int g = 0; g < 3; ++g) {
      float m = tot[g * 8];
#pragma unroll
      for (int e = 1; e < 8; ++e) m = fmaxf(m, tot[g * 8 + e]);
      float ex[8]; float s = 0.f;
#pragma unroll
      for (int e = 0; e < 8; ++e) { ex[e] = expf(tot[g * 8 + e] - m); s += ex[e]; }
      float inv = 1.f / s;
#pragma unroll
      for (int e = 0; e < 8; ++e) gout[g * 8 + e] = ex[e] * inv;
    }
  }
}

// ---------------------------------------------------------------------------
// GEMM, 256x256 tile, 8-phase schedule (T3+T4), XOR-swizzled LDS (T2),
// setprio around MFMA (T5).  C = relu(A @ Bt^T + bias), bf16 in/out.
//   A  [M][K] bf16 row-major; Bt [N][K] bf16 row-major.
//   512 threads = 8 waves (2M x 4N); per-wave C = 128x64; BK=64.
//   LDS 128 KiB: A0|A1|B0|B1, each [256][64] bf16, rows 128B.
//   Swizzle: phys kbyte P = logical kbyte L ^ ((row&7)<<4)  (involution);
//   applied on the global SOURCE of global_load_lds (linear dest) and on
//   every ds_read address.  K-tile t -> buffer t&1.  vmcnt(3) at ph4/ph8.
// Per-iteration stage schedule (quarters; each write trails its readers by
// >=1 phase-barrier; vmcnt ledger: 3 loads carried across each vmcnt(3)
// are exactly the not-yet-read A-quarters of the NEXT-next tile):
//   ph1: A(t+1)q3,B(t+1)q0,q1   ph2: B(t+1)q2,q3
//   ph3: A(t+2)q0,q1            ph4: A(t+2)q2          [vmcnt 3]
//   ph5: A(t+2)q3,B(t+2)q0      ph6: B(t+2)q1,q2
//   ph7: B(t+2)q3,A(t+3)q0      ph8: A(t+3)q1,q2       [vmcnt 3]
// ---------------------------------------------------------------------------
#define RD_A(buf, m, Pk) (*(const short8*)((buf) + aRow + (m) * 1024 + (Pk)))
#define RD_B(buf, n, Pk) (*(const short8*)((buf) + bRow + (n) * 1024 + (Pk)))

#define PHASE(AB, BB, m0v, m1v, LOADB, ...)                                    \
  {                                                                            \
    if (LOADB) {                                                               \
      _Pragma("unroll") for (int n = 0; n < 4; ++n) {                          \
        Bf[n][0] = RD_B(BB, n, Pk0);                                           \
        Bf[n][1] = RD_B(BB, n, Pk1);                                           \
      }                                                                        \
    }                                                                          \
    short8 A00 = RD_A(AB, m0v, Pk0), A01 = RD_A(AB, m0v, Pk1);                 \
    short8 A10 = RD_A(AB, m1v, Pk0), A11 = RD_A(AB, m1v, Pk1);                 \
    __VA_ARGS__;                                                               \
    BAR(); LGKM0();                                                            \
    __builtin_amdgcn_s_setprio(1);                                             \
    _Pragma("unroll") for (int n = 0; n < 4; ++n) {                            \
      acc[m0v][n] = __builtin_amdgcn_mfma_f32_16x16x32_bf16(A00, Bf[n][0], acc[m0v][n], 0, 0, 0); \
      acc[m0v][n] = __builtin_amdgcn_mfma_f32_16x16x32_bf16(A01, Bf[n][1], acc[m0v][n], 0, 0, 0); \
      acc[m1v][n] = __builtin_amdgcn_mfma_f32_16x16x32_bf16(A10, Bf[n][0], acc[m1v][n], 0, 0, 0); \
      acc[m1v][n] = __builtin_amdgcn_mfma_f32_16x16x32_bf16(A11, Bf[n][1], acc[m1v][n], 0, 0, 0); \
    }                                                                          \
    __builtin_amdgcn_s_setprio(0);                                             \
  }

__global__ __launch_bounds__(512, 2) void gemm8(
    const unsigned short* __restrict__ A, long sA,
    const unsigned short* __restrict__ Bt, long sB,
    const float* __restrict__ bias, long sBias,
    unsigned short* __restrict__ C, long sC,
    int K, int ldc) {
  __shared__ unsigned short lds[65536];   // 128 KiB

  const int z = blockIdx.z;
  A += (long)z * sA; Bt += (long)z * sB; bias += (long)z * sBias; C += (long)z * sC;

  const int tid = threadIdx.x;
  const int wid = tid >> 6, lane = tid & 63;
  const int wm = wid >> 2, wn = wid & 3;
  const int bm = blockIdx.x << 8, bn = blockIdx.y << 8;

  unsigned short* a0 = lds;
  unsigned short* a1 = lds + 16384;
  unsigned short* b0 = lds + 32768;
  unsigned short* b1 = lds + 49152;

  // staging: thread covers row (chunkbase + lane/8), 16B at physical kbyte
  // (lane&7)*16; source kbyte = phys ^ ((row&7)<<4).
  const int srcK = (((lane & 7) * 16) ^ ((lane >> 3) << 4)) >> 1;  // elems
  const int lsub = lane >> 3;
  const int ldst = lane * 8;                                       // shorts

  // fragment-read constants (shorts)
  const int aRow = (wm * 128 + (lane & 15)) * 64;
  const int bRow = (wn * 64 + (lane & 15)) * 64;
  const int Pk0 = ((((lane >> 4) << 4)) ^ ((lane & 7) << 4)) >> 1;
  const int Pk1 = ((64 + ((lane >> 4) << 4)) ^ ((lane & 7) << 4)) >> 1;

  auto stA = [&](unsigned short* dbuf, int tk, int q) {
    int rb = (wid < 4) ? (q * 32 + wid * 8) : (128 + q * 32 + (wid - 4) * 8);
    g2l16(A + (long)(bm + rb + lsub) * K + tk * 64 + srcK, dbuf + rb * 64 + ldst);
  };
  auto stB = [&](unsigned short* dbuf, int tk, int q) {
    int rb = q * 64 + wid * 8;
    g2l16(Bt + (long)(bn + rb + lsub) * K + tk * 64 + srcK, dbuf + rb * 64 + ldst);
  };

  f32x4 acc[8][4];
#pragma unroll
  for (int i = 0; i < 8; ++i)
#pragma unroll
    for (int j = 0; j < 4; ++j) acc[i][j] = (f32x4){0.f, 0.f, 0.f, 0.f};

  // prologue: tile0 full -> buf0; tile1 A q0..q2 -> buf1
  stA(a0, 0, 0); stA(a0, 0, 1); stA(a0, 0, 2); stA(a0, 0, 3);
  stB(b0, 0, 0); stB(b0, 0, 1); stB(b0, 0, 2); stB(b0, 0, 3);
  stA(a1, 1, 0); stA(a1, 1, 1); stA(a1, 1, 2);
  asm volatile("s_waitcnt vmcnt(0)" ::: "memory");
  BAR();

  const int NITER = K >> 7;   // K/128, two K-tiles per iteration
  for (int i = 0; i < NITER; ++i) {
    const int t1 = 2 * i + 1, t2 = 2 * i + 2, t3 = 2 * i + 3;
    const bool more = (i + 1 < NITER);
    short8 Bf[4][2];
    // ---- half 0: compute tile t from a0/b0 ----
    PHASE(a0, b0, 0, 1, 1, stA(a1, t1, 3); stB(b1, t1, 0); stB(b1, t1, 1));
    BAR();
    PHASE(a0, b0, 2, 3, 0, stB(b1, t1, 2); stB(b1, t1, 3));
    BAR();
    PHASE(a0, b0, 4, 5, 0, if (more) { stA(a0, t2, 0); stA(a0, t2, 1); });
    BAR();
    PHASE(a0, b0, 6, 7, 0, if (more) stA(a0, t2, 2));
    if (more) asm volatile("s_waitcnt vmcnt(3)" ::: "memory");
    else      asm volatile("s_waitcnt vmcnt(0)" ::: "memory");
    BAR();
    // ---- half 1: compute tile t+1 from a1/b1 ----
    PHASE(a1, b1, 0, 1, 1, if (more) { stA(a0, t2, 3); stB(b0, t2, 0); });
    BAR();
    PHASE(a1, b1, 2, 3, 0, if (more) { stB(b0, t2, 1); stB(b0, t2, 2); });
    BAR();
    PHASE(a1, b1, 4, 5, 0, if (more) { stB(b0, t2, 3); stA(a1, t3, 0); });
    BAR();
    PHASE(a1, b1, 6, 7, 0, if (more) { stA(a1, t3, 1); stA(a1, t3, 2); });
    if (more) asm volatile("s_waitcnt vmcnt(3)" ::: "memory");
    BAR();
  }

  // epilogue: bias + relu + bf16 store
#pragma unroll
  for (int m = 0; m < 8; ++m) {
    long row0 = bm + wm * 128 + m * 16 + (lane >> 4) * 4;
#pragma unroll
    for (int n = 0; n < 4; ++n) {
      long col = bn + wn * 64 + n * 16 + (lane & 15);
      float bv = bias[col];
#pragma unroll
      for (int r = 0; r < 4; ++r) {
        float v = acc[m][n][r] + bv;
        v = fmaxf(v, 0.f);
        C[(row0 + r) * ldc + col] = f2bf(v);
      }
    }
  }
}

// ---------------------------------------------------------------------------
// K4: mixed[g][bl][h] = sum_e gates[bl][g][e] * eo[bl][e][h]   (bf16 out)
// ---------------------------------------------------------------------------
__global__ __launch_bounds__(256) void k4_mix(const unsigned short* __restrict__ eo,
                                              const float* __restrict__ gates,
                                              unsigned short* __restrict__ mixed,
                                              int Bc) {
  int tid = threadIdx.x;
  int bl = blockIdx.x * 2 + (tid >> 7);
  int h8 = (tid & 127) * 8;
  const float* gp = gates + (long)bl * 24;
  float o0[8], o1[8], o2[8];
#pragma unroll
  for (int x = 0; x < 8; ++x) { o0[x] = 0.f; o1[x] = 0.f; o2[x] = 0.f; }
  const unsigned short* ep = eo + (long)bl * (NEXP * ESIZE) + h8;
#pragma unroll
  for (int e = 0; e < 8; ++e) {
    short8 v = *(const short8*)(ep + e * ESIZE);
    float g0 = gp[e], g1 = gp[8 + e], g2 = gp[16 + e];
#pragma unroll
    for (int x = 0; x < 8; ++x) {
      float fv = bf2f((unsigned short)v[x]);
      o0[x] += g0 * fv; o1[x] += g1 * fv; o2[x] += g2 * fv;
    }
  }
  long base = (long)bl * ESIZE + h8;
  short8 w0, w1, w2;
#pragma unroll
  for (int x = 0; x < 8; ++x) {
    w0[x] = (short)f2bf(o0[x]); w1[x] = (short)f2bf(o1[x]); w2[x] = (short)f2bf(o2[x]);
  }
  *(short8*)(mixed + base) = w0;
  *(short8*)(mixed + (long)Bc * ESIZE + base) = w1;
  *(short8*)(mixed + 2L * Bc * ESIZE + base) = w2;
}

// ---------------------------------------------------------------------------
// K6: output head + assembly
// ---------------------------------------------------------------------------
__global__ __launch_bounds__(256) void k6_out(const unsigned short* __restrict__ tower,
                                              const float* __restrict__ ow,
                                              const float* __restrict__ ob,
                                              float* __restrict__ out,
                                              int b0, int Bc) {
  int tid = threadIdx.x;
  int wid = tid >> 6, lane = tid & 63;
  int bl = blockIdx.x * 4 + wid;
  long b = (long)b0 + bl;
  float l0[3], l1[3];
#pragma unroll
  for (int g = 0; g < 3; ++g) {
    short8 t8 = *(const short8*)(tower + ((long)g * Bc + bl) * TSIZE + lane * 8);
    const float2* wp = (const float2*)(ow + g * (TSIZE * 2)) + lane * 8;
    float s0 = 0.f, s1 = 0.f;
#pragma unroll
    for (int x = 0; x < 8; ++x) {
      float a = bf2f((unsigned short)t8[x]);
      float2 w = wp[x];
      s0 += a * w.x; s1 += a * w.y;
    }
#pragma unroll
    for (int off = 32; off > 0; off >>= 1) {
      s0 += __shfl_xor(s0, off);
      s1 += __shfl_xor(s1, off);
    }
    l0[g] = s0 + ob[g * 2];
    l1[g] = s1 + ob[g * 2 + 1];
  }
  if (lane == 0) {
    float p0[3], p1[3];
#pragma unroll
    for (int g = 0; g < 3; ++g) {
      float d = l1[g] - l0[g];
      float e1 = 1.f / (1.f + expf(-d));
      float e0 = 1.f / (1.f + expf(d));
      p0[g] = fminf(fmaxf(e0, 1e-15f), 1.f - 1e-15f);
      p1[g] = fminf(fmaxf(e1, 1e-15f), 1.f - 1e-15f);
    }
    float ct = p1[0] * p1[1];
    out[b * 2]              = p0[0];
    out[b * 2 + 1]          = p1[0];
    out[32768 + b]          = p1[0];
    out[49152 + b * 2]      = p0[1];
    out[49152 + b * 2 + 1]  = p1[1];
    out[81920 + b]          = p1[1];
    out[98304 + b * 2]      = 1.f - ct;
    out[98304 + b * 2 + 1]  = ct;
    out[131072 + b]         = ct;
    out[147456 + b]         = p1[2];
  }
}

// ---------------------------------------------------------------------------
extern "C" void kernel_launch(void* const* d_in, const int* in_sizes, int n_in,
                              void* d_out, int out_size, void* d_ws, size_t ws_size,
                              hipStream_t stream) {
  (void)in_sizes; (void)n_in; (void)out_size;
  const int*   idx      = (const int*)d_in[0];
  const float* emb      = (const float*)d_in[1];
  const float* expert_w = (const float*)d_in[2];
  const float* expert_b = (const float*)d_in[3];
  const float* gate_w   = (const float*)d_in[4];
  const float* gate_b   = (const float*)d_in[5];
  const float* tower_w  = (const float*)d_in[6];
  const float* tower_b  = (const float*)d_in[7];
  const float* out_w    = (const float*)d_in[8];
  const float* out_b    = (const float*)d_in[9];
  float* out = (float*)d_out;

  // ---- workspace sizing: persistent weights + per-chunk regions
  const size_t P_EOW  = (size_t)NEXP * ESIZE * FEATD * 2;    // 48,234,496
  const size_t P_TWT  = (size_t)NGATE * TSIZE * ESIZE * 2;   //  3,145,728
  const size_t P      = P_EOW + P_TWT;                       // 51,380,224
  const size_t PER_B  = 31584;
  int NC = 1;
  while (NC < 64 && P + (size_t)(NUM_B / NC) * PER_B > ws_size) NC <<= 1;
  if (P + (size_t)(NUM_B / NC) * PER_B > ws_size) return;
  const int Bc = NUM_B / NC;

  char* ws = (char*)d_ws;
  unsigned short* eoW     = (unsigned short*)(ws);
  unsigned short* towerWt = (unsigned short*)(ws + P_EOW);
  size_t off = P;
  unsigned short* concat  = (unsigned short*)(ws + off); off += (size_t)Bc * 5888;
  float*          gates   = (float*)(ws + off);          off += (size_t)Bc * 96;
  unsigned short* eo      = (unsigned short*)(ws + off); off += (size_t)Bc * 16384;
  unsigned short* mixed   = (unsigned short*)(ws + off); off += (size_t)Bc * 6144;
  unsigned short* tower   = (unsigned short*)(ws + off);

  // W1/W2: weight transposes (f32 -> bf16 B^T form)
  k_transpose<<<dim3(ESIZE / 32, FEATD / 32, NEXP), dim3(32, 8), 0, stream>>>(
      expert_w, eoW, FEATD, ESIZE);
  k_transpose<<<dim3(TSIZE / 32, ESIZE / 32, NGATE), dim3(32, 8), 0, stream>>>(
      tower_w, towerWt, ESIZE, TSIZE);

  for (int c = 0; c < NC; ++c) {
    const int b0 = c * Bc;
    k1_pool<<<dim3(Bc / 8, FIELDS), 256, 0, stream>>>(idx, emb, concat, b0);
    k2_gates<<<dim3(Bc / 64), 256, 0, stream>>>(concat, gate_w, gate_b, gates);
    // K3: expert GEMM (z = expert), 256x256 8-phase
    gemm8<<<dim3(Bc / 256, ESIZE / 256, NEXP), 512, 0, stream>>>(
        concat, 0L, eoW, (long)ESIZE * FEATD, expert_b, (long)ESIZE,
        eo, (long)ESIZE, FEATD, NEXP * ESIZE);
    k4_mix<<<dim3(Bc / 2), 256, 0, stream>>>(eo, gates, mixed, Bc);
    // K5: tower GEMM (z = gate), 256x256 8-phase
    gemm8<<<dim3(Bc / 256, TSIZE / 256, NGATE), 512, 0, stream>>>(
        mixed, (long)Bc * ESIZE, towerWt, (long)TSIZE * ESIZE, tower_b, (long)TSIZE,
        tower, (long)Bc * TSIZE, ESIZE, TSIZE);
    k6_out<<<dim3(Bc / 4), 256, 0, stream>>>(tower, out_w, out_b, out, b0, Bc);
  }
}